// Round 1
// baseline (181.402 us; speedup 1.0000x reference)
//
#include <hip/hip_runtime.h>
#include <stdint.h>

#pragma clang fp contract(off)

#define A_TOTAL 147456   // 128*128*9
#define G 256
#define NB 9

// Base anchors (base_size=16, ratios {0.5,1,2}, scales {8,16,32}) — computed
// by hand from the reference _base_anchors() (np.round half-to-even: 11.5->12).
__constant__ float c_bx1[NB] = { -84.f, -176.f, -360.f,  -56.f, -120.f, -248.f,  -36.f,  -80.f, -168.f };
__constant__ float c_by1[NB] = { -40.f,  -88.f, -184.f,  -56.f, -120.f, -248.f,  -80.f, -168.f, -344.f };
__constant__ float c_bx2[NB] = {  99.f,  191.f,  375.f,   71.f,  135.f,  263.f,   51.f,   95.f,  183.f };
__constant__ float c_by2[NB] = {  55.f,  103.f,  199.f,   71.f,  135.f,  263.f,   95.f,  183.f,  359.f };
// Areas (w*h, exact integers < 2^24 so identical to fp32 computation)
__constant__ float c_area[NB] = { 17664.f, 70656.f, 282624.f, 16384.f, 65536.f, 262144.f, 15488.f, 61952.f, 247808.f };

// Monotone float -> uint mapping (total order matching float compare)
__device__ __forceinline__ unsigned int fenc(float f) {
    unsigned int u = __float_as_uint(f);
    return (u & 0x80000000u) ? ~u : (u | 0x80000000u);
}

__device__ __forceinline__ unsigned long long shfl_down_u64(unsigned long long v, int off) {
    unsigned int lo = (unsigned int)v;
    unsigned int hi = (unsigned int)(v >> 32);
    lo = __shfl_down(lo, off, 64);
    hi = __shfl_down(hi, off, 64);
    return ((unsigned long long)hi << 32) | lo;
}

// Kernel 1: per-gt argmax over anchors of IoU masked by `inside` (outside -> -1).
// One block per gt box. Encoding (fenc(iou)<<32)|~idx gives first-max-index
// semantics under unsigned max, matching jnp.argmax tie-breaking.
__global__ __launch_bounds__(1024) void k_gt_argmax(
    const float* __restrict__ gt, const float* __restrict__ meta,
    int* __restrict__ gt_idx)
{
    const int g = blockIdx.x;
    const float bx1 = gt[4*g+0], by1 = gt[4*g+1], bx2 = gt[4*g+2], by2 = gt[4*g+3];
    const float area_b = (bx2 - bx1 + 1.0f) * (by2 - by1 + 1.0f);
    const float H = meta[0], W = meta[1];

    unsigned long long best = 0ULL;  // 0 < any real encoding (fenc(-1)=0x407FFFFF)
    for (int n = threadIdx.x; n < A_TOTAL; n += 1024) {
        int k = n / 9;
        int a = n - 9 * k;
        float sx = (float)((k & 127) << 4);
        float sy = (float)((k >> 7) << 4);
        float ax1 = sx + c_bx1[a];
        float ay1 = sy + c_by1[a];
        float ax2 = sx + c_bx2[a];
        float ay2 = sy + c_by2[a];
        bool inside = (ax1 >= 0.0f) & (ay1 >= 0.0f) & (ax2 < W) & (ay2 < H);
        float area_a = c_area[a];
        float iw = fminf(ax2, bx2) - fmaxf(ax1, bx1) + 1.0f; iw = fmaxf(iw, 0.0f);
        float ih = fminf(ay2, by2) - fmaxf(ay1, by1) + 1.0f; ih = fmaxf(ih, 0.0f);
        float inter = iw * ih;
        float uni = fmaxf(area_a + area_b - inter, 1e-8f);
        float iou = inter / uni;
        float masked = inside ? iou : -1.0f;
        unsigned long long e = ((unsigned long long)fenc(masked) << 32) | (unsigned int)(~n);
        if (e > best) best = e;
    }

    // wave reduce (64 lanes)
    for (int off = 32; off >= 1; off >>= 1) {
        unsigned long long o = shfl_down_u64(best, off);
        if (o > best) best = o;
    }
    __shared__ unsigned long long red[16];
    int wave = threadIdx.x >> 6, lane = threadIdx.x & 63;
    if (lane == 0) red[wave] = best;
    __syncthreads();
    if (wave == 0) {
        unsigned long long v = (lane < 16) ? red[lane] : 0ULL;
        for (int off = 8; off >= 1; off >>= 1) {
            unsigned long long o = shfl_down_u64(v, off);
            if (o > v) v = o;
        }
        if (lane == 0) gt_idx[g] = (int)(~(unsigned int)(v & 0xffffffffULL));
    }
}

// Kernel 2: one thread per anchor. Per-anchor max/argmax over gt (unmasked),
// gt_argmax membership count, label ladder in reference order, bbox transform.
__global__ __launch_bounds__(256) void k_anchor(
    const float* __restrict__ gt, const float* __restrict__ meta,
    const int* __restrict__ gt_idx, float* __restrict__ out)
{
    __shared__ float4 sgt[G];
    __shared__ float  sarea[G];
    __shared__ int    sidx[G];
    const int tid = threadIdx.x;
    {
        float4 b = ((const float4*)gt)[tid];
        sgt[tid] = b;
        sarea[tid] = (b.z - b.x + 1.0f) * (b.w - b.y + 1.0f);
        sidx[tid] = gt_idx[tid];
    }
    __syncthreads();

    const float H = meta[0], W = meta[1];
    const int n = blockIdx.x * 256 + tid;
    int k = n / 9;
    int a = n - 9 * k;
    float sx = (float)((k & 127) << 4);
    float sy = (float)((k >> 7) << 4);
    float ax1 = sx + c_bx1[a];
    float ay1 = sy + c_by1[a];
    float ax2 = sx + c_bx2[a];
    float ay2 = sy + c_by2[a];
    bool inside = (ax1 >= 0.0f) & (ay1 >= 0.0f) & (ax2 < W) & (ay2 < H);
    float area_a = c_area[a];

    float bestv = -1.0f;
    int barg = 0;
    #pragma unroll 4
    for (int g = 0; g < G; ++g) {
        float4 bb = sgt[g];
        float iw = fminf(ax2, bb.z) - fmaxf(ax1, bb.x) + 1.0f; iw = fmaxf(iw, 0.0f);
        float ih = fminf(ay2, bb.w) - fmaxf(ay1, bb.y) + 1.0f; ih = fmaxf(ih, 0.0f);
        float inter = iw * ih;
        float uni = fmaxf(area_a + sarea[g] - inter, 1e-8f);
        float iou = inter / uni;
        if (iou > bestv) { bestv = iou; barg = g; }  // strict > : first max index
    }

    int count = 0;
    #pragma unroll 8
    for (int g = 0; g < G; ++g) count += (sidx[g] == n);

    // Label ladder, in exact reference order:
    float label = -1.0f;
    if (bestv < 0.3f) label = 0.0f;                          // NEG_OVERLAP
    if (count > 0) label = label + (float)count * (1.0f - label);  // .at[].add with dup accumulation
    if (bestv >= 0.7f) label = 1.0f;                         // POS_OVERLAP
    if (!inside) label = -1.0f;                              // applied last

    // bbox transform vs gt[argmax]
    float4 gb = sgt[barg];
    float ew = ax2 - ax1 + 1.0f;
    float eh = ay2 - ay1 + 1.0f;
    float ecx = ax1 + 0.5f * ew;
    float ecy = ay1 + 0.5f * eh;
    float gw = gb.z - gb.x + 1.0f;
    float gh = gb.w - gb.y + 1.0f;
    float gcx = gb.x + 0.5f * gw;
    float gcy = gb.y + 0.5f * gh;
    float t0 = (gcx - ecx) / ew;
    float t1 = (gcy - ecy) / eh;
    float t2 = logf(gw / ew);
    float t3 = logf(gh / eh);
    if (!inside) { t0 = 0.0f; t1 = 0.0f; t2 = 0.0f; t3 = 0.0f; }

    out[n] = label;
    ((float4*)(out + A_TOTAL))[n] = make_float4(t0, t1, t2, t3);
}

extern "C" void kernel_launch(void* const* d_in, const int* in_sizes, int n_in,
                              void* d_out, int out_size, void* d_ws, size_t ws_size,
                              hipStream_t stream) {
    // d_in[0] = scores (unused, shape only), d_in[1] = gt_boxes (1,256,4), d_in[2] = metadata (1,3)
    const float* gt   = (const float*)d_in[1];
    const float* meta = (const float*)d_in[2];
    float* out = (float*)d_out;
    int* gt_idx = (int*)d_ws;  // 256 ints

    k_gt_argmax<<<G, 1024, 0, stream>>>(gt, meta, gt_idx);
    k_anchor<<<A_TOTAL / 256, 256, 0, stream>>>(gt, meta, gt_idx, out);
}

// Round 2
// 123.171 us; speedup vs baseline: 1.4728x; 1.4728x over previous
//
#include <hip/hip_runtime.h>
#include <stdint.h>

#pragma clang fp contract(off)

#define A_TOTAL 147456   // 128*128*9
#define G 256

// Base anchors (base_size=16, ratios {0.5,1,2}, scales {8,16,32}) — from
// reference _base_anchors() (np.round half-to-even: 11.5->12).
__constant__ float c_bx1[9] = { -84.f, -176.f, -360.f,  -56.f, -120.f, -248.f,  -36.f,  -80.f, -168.f };
__constant__ float c_by1[9] = { -40.f,  -88.f, -184.f,  -56.f, -120.f, -248.f,  -80.f, -168.f, -344.f };
__constant__ float c_bx2[9] = {  99.f,  191.f,  375.f,   71.f,  135.f,  263.f,   51.f,   95.f,  183.f };
__constant__ float c_by2[9] = {  55.f,  103.f,  199.f,   71.f,  135.f,  263.f,   95.f,  183.f,  359.f };
__constant__ float c_area[9] = { 17664.f, 70656.f, 282624.f, 16384.f, 65536.f, 262144.f, 15488.f, 61952.f, 247808.f };

// Per-gt record staged in ws: box, area, winning (gt-argmax) anchor index.
// 32B-aligned so k2's uniform reads become s_load_dwordx4/x2.
struct __align__(32) GtRec { float x1, y1, x2, y2, area; int idx; int p0, p1; };

__device__ __forceinline__ unsigned int fenc(float f) {
    unsigned int u = __float_as_uint(f);
    return (u & 0x80000000u) ? ~u : (u | 0x80000000u);
}

__device__ __forceinline__ unsigned long long shfl_down_u64(unsigned long long v, int off) {
    unsigned int lo = (unsigned int)v;
    unsigned int hi = (unsigned int)(v >> 32);
    lo = __shfl_down(lo, off, 64);
    hi = __shfl_down(hi, off, 64);
    return ((unsigned long long)hi << 32) | lo;
}

// Kernel 1: per-gt argmax over anchors of IoU masked by `inside`.
// One block per gt. Only enumerates inside anchors whose window can intersect
// the gt (padded by 1 cell) — all others score <= 0 and provably can't win
// (max masked iou > 0 for every gt). Candidates get the exact reference iou;
// (fenc(iou)<<32)|~n under u64-max == first-max-index semantics.
__global__ __launch_bounds__(256) void k_gt(
    const float* __restrict__ gt, const float* __restrict__ meta,
    GtRec* __restrict__ recs)
{
    const int g = blockIdx.x;
    const float gx1 = gt[4*g+0], gy1 = gt[4*g+1], gx2 = gt[4*g+2], gy2 = gt[4*g+3];
    const float area_b = (gx2 - gx1 + 1.0f) * (gy2 - gy1 + 1.0f);
    const float H = meta[0], W = meta[1];
    const int tx = threadIdx.x & 15, ty = threadIdx.x >> 4;

    constexpr int ibx1[9] = {-84,-176,-360,-56,-120,-248,-36,-80,-168};
    constexpr int iby1[9] = {-40,-88,-184,-56,-120,-248,-80,-168,-344};
    constexpr int ibx2[9] = { 99, 191, 375, 71, 135, 263, 51, 95, 183};
    constexpr int iby2[9] = { 55, 103, 199, 71, 135, 263, 95, 183, 359};
    constexpr int iarea[9] = {17664,70656,282624,16384,65536,262144,15488,61952,247808};

    unsigned long long best = 0ULL;  // < any real encoding
    #pragma unroll
    for (int a = 0; a < 9; ++a) {
        // inside range (anchor fully in image)
        const int xlo_in = (-ibx1[a] + 15) >> 4;
        const int ylo_in = (-iby1[a] + 15) >> 4;
        const int xhi_in = (int)floorf((W - 1.0f - (float)ibx2[a]) * 0.0625f);
        const int yhi_in = (int)floorf((H - 1.0f - (float)iby2[a]) * 0.0625f);
        // overlap range (padded 1 cell each side, conservative)
        int xlo = max(max((int)floorf((gx1 - (float)ibx2[a]) * 0.0625f) - 1, xlo_in), 0);
        int xhi = min(min((int)floorf((gx2 - (float)ibx1[a]) * 0.0625f) + 1, xhi_in), 127);
        int ylo = max(max((int)floorf((gy1 - (float)iby2[a]) * 0.0625f) - 1, ylo_in), 0);
        int yhi = min(min((int)floorf((gy2 - (float)iby1[a]) * 0.0625f) + 1, yhi_in), 127);
        const float fa = (float)iarea[a];

        for (int iy = ylo + ty; iy <= yhi; iy += 16) {
            const float ay1 = (float)((iy << 4) + iby1[a]);
            const float ay2 = (float)((iy << 4) + iby2[a]);
            float ih = fminf(ay2, gy2) - fmaxf(ay1, gy1) + 1.0f; ih = fmaxf(ih, 0.0f);
            for (int ix = xlo + tx; ix <= xhi; ix += 16) {
                const float ax1 = (float)((ix << 4) + ibx1[a]);
                const float ax2 = (float)((ix << 4) + ibx2[a]);
                bool inside = (ax1 >= 0.0f) & (ay1 >= 0.0f) & (ax2 < W) & (ay2 < H);
                float iw = fminf(ax2, gx2) - fmaxf(ax1, gx1) + 1.0f; iw = fmaxf(iw, 0.0f);
                float inter = iw * ih;
                float uni = fmaxf(fa + area_b - inter, 1e-8f);
                float iou = inter / uni;
                float m = inside ? iou : -1.0f;
                int n = ((iy << 7) + ix) * 9 + a;
                unsigned long long e = ((unsigned long long)fenc(m) << 32) | (unsigned int)(~n);
                if (e > best) best = e;
            }
        }
    }

    // block reduction (4 waves)
    for (int off = 32; off >= 1; off >>= 1) {
        unsigned long long o = shfl_down_u64(best, off);
        if (o > best) best = o;
    }
    __shared__ unsigned long long red[4];
    const int wave = threadIdx.x >> 6, lane = threadIdx.x & 63;
    if (lane == 0) red[wave] = best;
    __syncthreads();
    if (threadIdx.x == 0) {
        unsigned long long v = red[0];
        if (red[1] > v) v = red[1];
        if (red[2] > v) v = red[2];
        if (red[3] > v) v = red[3];
        GtRec r;
        r.x1 = gx1; r.y1 = gy1; r.x2 = gx2; r.y2 = gy2;
        r.area = area_b;
        r.idx = (int)(~(unsigned int)(v & 0xffffffffULL));
        r.p0 = 0; r.p1 = 0;
        recs[g] = r;
    }
}

// Kernel 2: one thread per anchor. gt records read with wave-uniform index
// -> scalar (s_load) path, no LDS. Membership test fused into the same loop.
__global__ __launch_bounds__(256) void k_anchor(
    const GtRec* __restrict__ recs, const float* __restrict__ meta,
    float* __restrict__ out)
{
    const float H = meta[0], W = meta[1];
    const int n = blockIdx.x * 256 + threadIdx.x;
    int k = n / 9;
    int a = n - 9 * k;
    float sx = (float)((k & 127) << 4);
    float sy = (float)((k >> 7) << 4);
    float ax1 = sx + c_bx1[a];
    float ay1 = sy + c_by1[a];
    float ax2 = sx + c_bx2[a];
    float ay2 = sy + c_by2[a];
    bool inside = (ax1 >= 0.0f) & (ay1 >= 0.0f) & (ax2 < W) & (ay2 < H);
    float area_a = c_area[a];

    float bestv = -1.0f;
    int barg = 0;
    float cntf = 0.0f;
    #pragma unroll 8
    for (int g = 0; g < G; ++g) {
        GtRec r = recs[g];
        float iw = fminf(ax2, r.x2) - fmaxf(ax1, r.x1) + 1.0f; iw = fmaxf(iw, 0.0f);
        float ih = fminf(ay2, r.y2) - fmaxf(ay1, r.y1) + 1.0f; ih = fmaxf(ih, 0.0f);
        float inter = iw * ih;
        float uni = fmaxf(area_a + r.area - inter, 1e-8f);
        float iou = inter / uni;
        if (iou > bestv) { bestv = iou; barg = g; }   // strict > : first max index
        cntf += (r.idx == n) ? 1.0f : 0.0f;
    }

    // Label ladder in exact reference order. .at[].add with duplicate indices
    // accumulates: new = old + count*(1-old); old in {-1,0} so exact in fp32.
    float label = -1.0f;
    if (bestv < 0.3f) label = 0.0f;            // NEG_OVERLAP
    label = label + cntf * (1.0f - label);     // gt-argmax scatter-add
    if (bestv >= 0.7f) label = 1.0f;           // POS_OVERLAP
    if (!inside) label = -1.0f;                // applied last

    // bbox transform vs gt[argmax]
    GtRec gb = recs[barg];
    float ew = ax2 - ax1 + 1.0f;
    float eh = ay2 - ay1 + 1.0f;
    float ecx = ax1 + 0.5f * ew;
    float ecy = ay1 + 0.5f * eh;
    float gw = gb.x2 - gb.x1 + 1.0f;
    float gh = gb.y2 - gb.y1 + 1.0f;
    float gcx = gb.x1 + 0.5f * gw;
    float gcy = gb.y1 + 0.5f * gh;
    float t0 = (gcx - ecx) / ew;
    float t1 = (gcy - ecy) / eh;
    float t2 = logf(gw / ew);
    float t3 = logf(gh / eh);
    if (!inside) { t0 = 0.0f; t1 = 0.0f; t2 = 0.0f; t3 = 0.0f; }

    out[n] = label;
    ((float4*)(out + A_TOTAL))[n] = make_float4(t0, t1, t2, t3);
}

extern "C" void kernel_launch(void* const* d_in, const int* in_sizes, int n_in,
                              void* d_out, int out_size, void* d_ws, size_t ws_size,
                              hipStream_t stream) {
    // d_in[0] = scores (unused), d_in[1] = gt_boxes (1,256,4), d_in[2] = metadata (1,3)
    const float* gt   = (const float*)d_in[1];
    const float* meta = (const float*)d_in[2];
    float* out = (float*)d_out;
    GtRec* recs = (GtRec*)d_ws;   // 256 * 32B = 8 KB

    k_gt<<<G, 256, 0, stream>>>(gt, meta, recs);
    k_anchor<<<A_TOTAL / 256, 256, 0, stream>>>(recs, meta, out);
}